// Round 3
// baseline (540.372 us; speedup 1.0000x reference)
//
#include <hip/hip_runtime.h>

#define IN_CH 128
#define OUT_CH 256
#define NPB 4          // nodes per block == waves per block
#define BLK 256        // 4 waves
#define BLK_SCAN 1024

__global__ void zero_i32(int* __restrict__ p, int n) {
  int i = blockIdx.x * blockDim.x + threadIdx.x;
  if (i < n) p[i] = 0;
}

__global__ void hist_kernel(const int* __restrict__ col, int E, int* __restrict__ count) {
  int i = blockIdx.x * blockDim.x + threadIdx.x;
  if (i < E) atomicAdd(&count[col[i]], 1);
}

// Wt[c][t] = W[t][c]  (128KB, L2-resident, one-shot)
__global__ void transpose_w(const float* __restrict__ W, float* __restrict__ Wt) {
  int i = blockIdx.x * blockDim.x + threadIdx.x;  // 32768 elements
  if (i < IN_CH * OUT_CH) {
    int c = i >> 8;           // / OUT_CH
    int t = i & (OUT_CH - 1);
    Wt[i] = W[t * IN_CH + c];
  }
}

// shfl-based block scan: 3 barriers
__global__ __launch_bounds__(BLK_SCAN) void scan_block_kernel(
    const int* __restrict__ count, int N, int* __restrict__ excl, int* __restrict__ bsum) {
  __shared__ int wsum[16];
  const int tid = threadIdx.x;
  const int i = blockIdx.x * BLK_SCAN + tid;
  const int v = (i < N) ? count[i] : 0;
  int x = v;
#pragma unroll
  for (int d = 1; d < 64; d <<= 1) {
    int t = __shfl_up(x, d, 64);
    if ((tid & 63) >= d) x += t;
  }
  if ((tid & 63) == 63) wsum[tid >> 6] = x;
  __syncthreads();
  if (tid < 16) {
    int s = wsum[tid];
#pragma unroll
    for (int d = 1; d < 16; d <<= 1) {
      int t = __shfl_up(s, d, 16);
      if (tid >= d) s += t;
    }
    wsum[tid] = s;  // inclusive wave sums
  }
  __syncthreads();
  const int w = tid >> 6;
  const int prefix = (w == 0) ? 0 : wsum[w - 1];
  if (i < N) excl[i] = prefix + x - v;
  if (tid == BLK_SCAN - 1) bsum[blockIdx.x] = prefix + x;
}

__global__ void scan_bsum_kernel(int* __restrict__ bsum, int nb) {
  __shared__ int tmp[256];
  const int tid = threadIdx.x;
  int run = 0;
  for (int s = 0; s < nb; s += 256) {
    int v = (s + tid < nb) ? bsum[s + tid] : 0;
    tmp[tid] = v;
    __syncthreads();
    for (int d = 1; d < 256; d <<= 1) {
      int t = (tid >= d) ? tmp[tid - d] : 0;
      __syncthreads();
      tmp[tid] += t;
      __syncthreads();
    }
    if (s + tid < nb) bsum[s + tid] = run + tmp[tid] - v;
    run += tmp[255];
    __syncthreads();
  }
}

__global__ void add_offsets_kernel(int* __restrict__ excl, const int* __restrict__ bsum,
                                   int* __restrict__ cursor, int N) {
  int i = blockIdx.x * blockDim.x + threadIdx.x;
  if (i < N) {
    int o = excl[i] + bsum[i / BLK_SCAN];
    excl[i] = o;
    cursor[i] = o;
  }
}

__global__ void scatter_kernel(const int* __restrict__ col, int E,
                               int* __restrict__ cursor, int* __restrict__ sorted) {
  int i = blockIdx.x * blockDim.x + threadIdx.x;
  if (i < E) {
    int c = col[i];
    int pos = atomicAdd(&cursor[c], 1);
    sorted[pos] = i;
  }
}

// Phase 1: one node per FULL WAVE; 16 rows in flight per iteration
//   (64 lanes x float2 = one 512B row per load instruction).
//   sorted[] batch for the NEXT iteration is prefetched inside the loop.
//   Tail uses a wave-uniform branch; clamped duplicate loads are L2 hits.
// Phase 2: thread t = output channel; Wt[c][t] reads are lane-coalesced.
__global__ __launch_bounds__(BLK) void gather_project_kernel(
    const float* __restrict__ te, const int* __restrict__ offsets,
    const int* __restrict__ cend, const int* __restrict__ sorted,
    const float* __restrict__ Wt, const float* __restrict__ bias,
    float* __restrict__ out, int N) {
  __shared__ float agg[NPB][IN_CH];  // 2 KB
  const int g    = threadIdx.x >> 6;  // wave id == node slot
  const int lane = threadIdx.x & 63;
  const int base = blockIdx.x * NPB;
  const int n = base + g;

  float ax = 0.f, ay = 0.f;
  if (n < N) {
    const int s = offsets[n];
    const int e = cend[n];
    if (s < e) {
      const size_t co = (size_t)(lane * 2);
      int my = 0;
      if (lane < 16) {
        int idx = s + lane;
        my = sorted[idx < e ? idx : (e - 1)];
      }
      for (int i = s; i < e; i += 16) {
#define EID(j) __shfl(my, j, 64)
        const float2 t0  = *(const float2*)(te + (size_t)EID(0)  * IN_CH + co);
        const float2 t1  = *(const float2*)(te + (size_t)EID(1)  * IN_CH + co);
        const float2 t2  = *(const float2*)(te + (size_t)EID(2)  * IN_CH + co);
        const float2 t3  = *(const float2*)(te + (size_t)EID(3)  * IN_CH + co);
        const float2 t4  = *(const float2*)(te + (size_t)EID(4)  * IN_CH + co);
        const float2 t5  = *(const float2*)(te + (size_t)EID(5)  * IN_CH + co);
        const float2 t6  = *(const float2*)(te + (size_t)EID(6)  * IN_CH + co);
        const float2 t7  = *(const float2*)(te + (size_t)EID(7)  * IN_CH + co);
        const float2 t8  = *(const float2*)(te + (size_t)EID(8)  * IN_CH + co);
        const float2 t9  = *(const float2*)(te + (size_t)EID(9)  * IN_CH + co);
        const float2 t10 = *(const float2*)(te + (size_t)EID(10) * IN_CH + co);
        const float2 t11 = *(const float2*)(te + (size_t)EID(11) * IN_CH + co);
        const float2 t12 = *(const float2*)(te + (size_t)EID(12) * IN_CH + co);
        const float2 t13 = *(const float2*)(te + (size_t)EID(13) * IN_CH + co);
        const float2 t14 = *(const float2*)(te + (size_t)EID(14) * IN_CH + co);
        const float2 t15 = *(const float2*)(te + (size_t)EID(15) * IN_CH + co);
#undef EID
        // prefetch next sorted batch while row loads are in flight
        int nxt = 0;
        {
          const int ib = i + 16;
          if (lane < 16 && ib < e) {
            int idx = ib + lane;
            nxt = sorted[idx < e ? idx : (e - 1)];
          }
        }
        const int rem = e - i;  // wave-uniform
        if (rem >= 16) {
          ax += (t0.x + t1.x) + (t2.x + t3.x) + (t4.x + t5.x) + (t6.x + t7.x) +
                (t8.x + t9.x) + (t10.x + t11.x) + (t12.x + t13.x) + (t14.x + t15.x);
          ay += (t0.y + t1.y) + (t2.y + t3.y) + (t4.y + t5.y) + (t6.y + t7.y) +
                (t8.y + t9.y) + (t10.y + t11.y) + (t12.y + t13.y) + (t14.y + t15.y);
        } else {
          ax += t0.x; ay += t0.y;
#define ACC(j, tj) { const float c = (rem > j) ? 1.f : 0.f; \
                     ax = fmaf(c, tj.x, ax); ay = fmaf(c, tj.y, ay); }
          ACC(1, t1)  ACC(2, t2)  ACC(3, t3)  ACC(4, t4)  ACC(5, t5)
          ACC(6, t6)  ACC(7, t7)  ACC(8, t8)  ACC(9, t9)  ACC(10, t10)
          ACC(11, t11) ACC(12, t12) ACC(13, t13) ACC(14, t14) ACC(15, t15)
#undef ACC
        }
        my = nxt;
      }
    }
  }
  {
    float2 r; r.x = ax; r.y = ay;
    *(float2*)(&agg[g][lane * 2]) = r;
  }
  __syncthreads();

  // Phase 2: projection. t = output channel; Wt[c*256 + t] coalesced.
  const int t = threadIdx.x;
  float acc[NPB];
#pragma unroll
  for (int gg = 0; gg < NPB; ++gg) acc[gg] = 0.f;
#pragma unroll 8
  for (int c4 = 0; c4 < IN_CH / 4; ++c4) {
    const int c = c4 * 4;
    const float w0 = Wt[(size_t)(c + 0) * OUT_CH + t];
    const float w1 = Wt[(size_t)(c + 1) * OUT_CH + t];
    const float w2 = Wt[(size_t)(c + 2) * OUT_CH + t];
    const float w3 = Wt[(size_t)(c + 3) * OUT_CH + t];
#pragma unroll
    for (int gg = 0; gg < NPB; ++gg) {
      const float4 a = *(const float4*)(&agg[gg][c]);
      acc[gg] = fmaf(w0, a.x, fmaf(w1, a.y, fmaf(w2, a.z, fmaf(w3, a.w, acc[gg]))));
    }
  }
  const float bv = bias[t];
#pragma unroll
  for (int gg = 0; gg < NPB; ++gg) {
    const int nn = base + gg;
    if (nn < N) out[(size_t)nn * OUT_CH + t] = acc[gg] + bv;
  }
}

extern "C" void kernel_launch(void* const* d_in, const int* in_sizes, int n_in,
                              void* d_out, int out_size, void* d_ws, size_t ws_size,
                              hipStream_t stream) {
  const int* edge_index = (const int*)d_in[0];
  const float* te       = (const float*)d_in[1];
  const float* W        = (const float*)d_in[3];
  const float* bias     = (const float*)d_in[4];
  float* out            = (float*)d_out;

  const int E = in_sizes[0] / 2;
  const int N = out_size / OUT_CH;
  const int* col = edge_index + E;

  int* ws      = (int*)d_ws;
  int* count   = ws;                    // N
  int* offsets = ws + N;                // N
  int* cursor  = ws + 2 * N;            // N
  int* bsum    = ws + 3 * N;            // 4096
  int* sorted  = ws + 3 * N + 4096;     // E
  float* Wt    = (float*)(ws + 3 * N + 4096 + E);  // 32768 floats

  const int nb = (N + BLK_SCAN - 1) / BLK_SCAN;

  hipLaunchKernelGGL(zero_i32, dim3((N + 255) / 256), dim3(256), 0, stream, count, N);
  hipLaunchKernelGGL(transpose_w, dim3((IN_CH * OUT_CH + 255) / 256), dim3(256), 0, stream, W, Wt);
  hipLaunchKernelGGL(hist_kernel, dim3((E + 255) / 256), dim3(256), 0, stream, col, E, count);
  hipLaunchKernelGGL(scan_block_kernel, dim3(nb), dim3(BLK_SCAN), 0, stream, count, N, offsets, bsum);
  hipLaunchKernelGGL(scan_bsum_kernel, dim3(1), dim3(256), 0, stream, bsum, nb);
  hipLaunchKernelGGL(add_offsets_kernel, dim3((N + 255) / 256), dim3(256), 0, stream,
                     offsets, bsum, cursor, N);
  hipLaunchKernelGGL(scatter_kernel, dim3((E + 255) / 256), dim3(256), 0, stream, col, E, cursor, sorted);
  hipLaunchKernelGGL(gather_project_kernel, dim3((N + NPB - 1) / NPB), dim3(BLK), 0, stream,
                     te, offsets, cursor, sorted, Wt, bias, out, N);
}